// Round 6
// baseline (305.887 us; speedup 1.0000x reference)
//
#include <hip/hip_runtime.h>
#include <cmath>

#define DEV __device__ __forceinline__

typedef __bf16 bf16x8 __attribute__((ext_vector_type(8)));
typedef float f32x4 __attribute__((ext_vector_type(4)));
typedef unsigned int u32;
typedef unsigned short u16;

DEV u16 f2bf(float f) {
  union { float f; u32 u; } v;
  v.f = f;
  u32 u = v.u;
  u += 0x7fffu + ((u >> 16) & 1u);   // RNE
  return (u16)(u >> 16);
}

// async global->LDS, 16B per lane; LDS dst is wave-uniform base + lane*16
DEV void async16(const void* g, void* l) {
  __builtin_amdgcn_global_load_lds((const __attribute__((address_space(1))) u32*)g,
                                   (__attribute__((address_space(3))) u32*)l, 16, 0, 0);
}

enum { ACT_ID = 0, ACT_ELU1 = 1, ACT_GELU = 2, ACT_ELU1S = 3 };
enum { OM_ROW = 0, OM_VT = 1 };   // row-major | vT[b][h][e][m]

DEV float apply_act(int ACT, float v, float scale) {
  if (ACT == ACT_ELU1)  return (v > 0.f) ? (v + 1.f) : __expf(v);
  if (ACT == ACT_GELU)  return 0.5f * v * (1.f + erff(v * 0.7071067811865475f));
  if (ACT == ACT_ELU1S) return ((v > 0.f) ? (v + 1.f) : __expf(v)) * scale;
  return v;
}

// ---------------------------------------------------------------------------
// m97-style GEMM. A: [R,K] fp32 (AFP32=1: VGPR-staged, cvt-during-staging) or
// bf16 (async16). LDS A layout is bf16 [row][32] in BOTH cases.
// Bt: [NC,K] bf16 (= W^T), async16. 4 waves, wave tile 64x64, BK=32.
// ---------------------------------------------------------------------------
template <int BM, int BN, int K, int WR, int WC, int ACT, int OBF16, int OMODE, int AFP32>
__global__ __launch_bounds__(256)
void gemm_bf16(const void* __restrict__ Av, const u16* __restrict__ Bt,
               const float* __restrict__ bias, void* __restrict__ Yv,
               int NC, float scale)
{
  constexpr int BI = BN / 64;
  // LDS: A bf16 (BM*32 u16) + B (BN*32 u16); OM_VT bounce needs 4*64*72 u16
  constexpr int SBASE = BM * 32 + BN * 32;
  constexpr int SBSZ = (OMODE == OM_VT && 4 * 64 * 72 > SBASE) ? 4 * 64 * 72 : SBASE;
  __shared__ __align__(16) u16 SB[SBSZ];
  u16* AsU = SB;
  u16* Bs = SB + BM * 32;
  static_assert(WR * WC == 4, "4 waves");

  const int tid = threadIdx.x;
  const int wv = tid >> 6, lane = tid & 63;
  const int wr = wv / WC, wc = wv % WC;
  const int lrow = lane & 15, lq = lane >> 4;
  const int c0 = blockIdx.x * BN;
  const long r0 = (long)blockIdx.y * BM;
  const float* Af = (const float*)Av;
  const u16* Ah = (const u16*)Av;

  f32x4 acc[4][4] = {};

  for (int kt = 0; kt < K; kt += 32) {
    if (AFP32) {
      // VGPR staging: 8 fp32/thread -> RNE cvt -> one b128 bf16 LDS write
      const int row = tid >> 2, kq = tid & 3;
#pragma unroll
      for (int it = 0; it < BM / 64; ++it) {
        const int r = it * 64 + row;
        const float* g = Af + (r0 + r) * K + kt + kq * 8;
        float4 lo = *(const float4*)g;
        float4 hi = *(const float4*)(g + 4);
        union { ushort4 h[2]; uint4 q; } pk;
        pk.h[0].x = f2bf(lo.x); pk.h[0].y = f2bf(lo.y);
        pk.h[0].z = f2bf(lo.z); pk.h[0].w = f2bf(lo.w);
        pk.h[1].x = f2bf(hi.x); pk.h[1].y = f2bf(hi.y);
        pk.h[1].z = f2bf(hi.z); pk.h[1].w = f2bf(hi.w);
        *(uint4*)&AsU[r * 32 + kq * 8] = pk.q;
      }
    } else {
#pragma unroll
      for (int i = 0; i < BM / 64; ++i) {
        const int s = (wv * (BM / 64) + i) * 64 + lane;
        async16(Ah + (r0 + (s >> 2)) * (long)K + kt + (s & 3) * 8,
                &AsU[(wv * (BM / 64) + i) * 512]);
      }
    }
#pragma unroll
    for (int i = 0; i < BI; ++i) {
      const int s = (wv * BI + i) * 64 + lane;
      async16(Bt + ((long)c0 + (s >> 2)) * K + kt + (s & 3) * 8,
              &Bs[(wv * BI + i) * 512]);
    }
    __syncthreads();
    bf16x8 af[4], bfr[4];
#pragma unroll
    for (int i = 0; i < 4; ++i)
      af[i] = *(const bf16x8*)&AsU[(wr * 64 + i * 16 + lrow) * 32 + lq * 8];
#pragma unroll
    for (int j = 0; j < 4; ++j)
      bfr[j] = *(const bf16x8*)&Bs[(wc * 64 + j * 16 + lrow) * 32 + lq * 8];
#pragma unroll
    for (int i = 0; i < 4; ++i)
#pragma unroll
      for (int j = 0; j < 4; ++j)
        acc[i][j] = __builtin_amdgcn_mfma_f32_16x16x32_bf16(af[i], bfr[j], acc[i][j], 0, 0, 0);
    __syncthreads();
  }

  float* Yf = (float*)Yv;
  u16* Yh = (u16*)Yv;

  if (OMODE == OM_ROW) {
#pragma unroll
    for (int i = 0; i < 4; ++i) {
#pragma unroll
      for (int j = 0; j < 4; ++j) {
        const int col = c0 + wc * 64 + j * 16 + lrow;
        const float bv = bias[col];
#pragma unroll
        for (int p = 0; p < 4; ++p) {
          const float o = apply_act(ACT, acc[i][j][p] + bv, scale);
          const long row = r0 + wr * 64 + i * 16 + lq * 4 + p;
          const long yi = row * NC + col;
          if (OBF16) Yh[yi] = f2bf(o);
          else       Yf[yi] = o;
        }
      }
    }
  } else {
    // OM_VT: per-wave LDS bounce (64 e x 64 m, pad 72), then coalesced m-runs.
    // Loop-end barrier already ensures all waves finished LDS fragment reads;
    // each wave writes/reads only its own 4608-u16 region -> no extra barrier.
    u16* LTv = SB + wv * 4608;
#pragma unroll
    for (int i = 0; i < 4; ++i) {
#pragma unroll
      for (int j = 0; j < 4; ++j) {
        const int col = c0 + wc * 64 + j * 16 + lrow;
        const float bv = bias[col];
        ushort4 w;
        w.x = f2bf(apply_act(ACT, acc[i][j][0] + bv, scale));
        w.y = f2bf(apply_act(ACT, acc[i][j][1] + bv, scale));
        w.z = f2bf(apply_act(ACT, acc[i][j][2] + bv, scale));
        w.w = f2bf(apply_act(ACT, acc[i][j][3] + bv, scale));
        const int e_l = j * 16 + lrow;
        const int m_l = i * 16 + lq * 4;
        *(ushort4*)&LTv[e_l * 72 + m_l] = w;
      }
    }
    const int b = (int)(r0 >> 12);
    const int h = (c0 + wc * 64) >> 6;
    const int mg0 = (int)(r0 & 4095) + wr * 64;
#pragma unroll
    for (int ps = 0; ps < 8; ++ps) {
      const int e = ps * 8 + (lane >> 3);
      const int mq = (lane & 7) * 8;
      uint4 v = *(const uint4*)&LTv[e * 72 + mq];
      *(uint4*)(Yh + (((long)b * 8 + h) * 64 + e) * 4096 + mg0 + mq) = v;
    }
  }
}

// ---------------------------------------------------------------------------
// weight transpose+convert: W [K,N] fp32 -> Wt [N,K] bf16
// ---------------------------------------------------------------------------
struct TArgs {
  const float* src[6];
  u16* dst[6];
  int K[6];
  int N[6];
};
__global__ __launch_bounds__(256)
void transpose_w(TArgs a)
{
  const int m = blockIdx.z;
  const int K = a.K[m], N = a.N[m];
  const int kt = blockIdx.y * 64, nt = blockIdx.x * 64;
  if (kt >= K || nt >= N) return;
  const float* src = a.src[m];
  u16* dst = a.dst[m];
  __shared__ u16 t[64][72];
  const int tx = threadIdx.x & 15, ty = threadIdx.x >> 4;
#pragma unroll
  for (int rr = 0; rr < 64; rr += 16) {
    const int k = kt + ty + rr;
    float4 v = *(const float4*)(src + (long)k * N + nt + tx * 4);
    t[tx * 4 + 0][ty + rr] = f2bf(v.x);
    t[tx * 4 + 1][ty + rr] = f2bf(v.y);
    t[tx * 4 + 2][ty + rr] = f2bf(v.z);
    t[tx * 4 + 3][ty + rr] = f2bf(v.w);
  }
  __syncthreads();
#pragma unroll
  for (int it = 0; it < 2; ++it) {
    const int s = threadIdx.x + it * 256;
    const int r = s >> 3, c = (s & 7) * 8;
    ushort4 u0 = *(ushort4*)&t[r][c];
    ushort4 u1 = *(ushort4*)&t[r][c + 4];
    *(ushort4*)(dst + (long)(nt + r) * K + kt + c) = u0;
    *(ushort4*)(dst + (long)(nt + r) * K + kt + c + 4) = u1;
  }
}

// ---------------------------------------------------------------------------
// fused MLP: per (b,h, 128 m): kaT[bh][d][m] = (elu(gelu(k@W1+b1)@W2+b2)+1)/M
// pass1: C[c][m] = W1T(A) x kact(B)
// pass2: C[m][d] = hid(A) x W2T(B)  -> lane holds 4 contiguous m -> vector
//        LDS bounce LT2[d][m] -> fully coalesced kaT writes.
// LDS (u16): As[128][72] @0 | W1p[128][72] @9216 | W2p[64][136] @18432
//            hid[128][136] overlays [0,17408) after pass1; LT2[64][136] after pass2.
// ---------------------------------------------------------------------------
__global__ __launch_bounds__(256)
void mlp_fused(const u16* __restrict__ kact, const u16* __restrict__ W1T,
               const u16* __restrict__ W2T, const float* __restrict__ b1,
               const float* __restrict__ b2, u16* __restrict__ kaT, float invM)
{
  __shared__ __align__(16) u16 SB[27136];
  u16* As  = SB;            // [128 m][72], data in [.][0,64)
  u16* W1p = SB + 9216;     // [128 c][72], data in [.][0,64)
  u16* W2p = SB + 18432;    // [64 d][136], data in [.][0,128)
  u16* hid = SB;            // [128 m][136] overlay
  u16* LT2 = SB;            // [64 d][136 m-pad] overlay (after pass2)

  const int tid = threadIdx.x, wv = tid >> 6, lane = tid & 63;
  const int lrow = lane & 15, lq = lane >> 4;
  const int bh = blockIdx.y, b = bh >> 3, h = bh & 7;
  const int m0 = blockIdx.x * 128;
  const long kbase = ((long)b * 4096 + m0) * 512 + h * 64;

  // ---- stage ----
#pragma unroll
  for (int i = 0; i < 4; ++i) {          // As: 1024 chunks of 8 u16
    const int c = i * 256 + tid;
    const int row = c >> 3, p = c & 7;
    uint4 v = *(const uint4*)(kact + kbase + (long)row * 512 + p * 8);
    *(uint4*)&As[row * 72 + p * 8] = v;
  }
#pragma unroll
  for (int i = 0; i < 4; ++i) {          // W1p: 1024 chunks (128 rows x 8)
    const int c = i * 256 + tid;
    const int row = c >> 3, p = c & 7;
    uint4 v = *(const uint4*)(W1T + c * 8);
    *(uint4*)&W1p[row * 72 + p * 8] = v;
  }
#pragma unroll
  for (int i = 0; i < 4; ++i) {          // W2p: 1024 chunks (64 rows x 16)
    const int c = i * 256 + tid;
    const int row = c >> 4, p = c & 15;
    uint4 v = *(const uint4*)(W2T + c * 8);
    *(uint4*)&W2p[row * 136 + p * 8] = v;
  }
  __syncthreads();

  // ---- pass 1: [128 c] x [128 m], K=64 ----
  const int c0 = (wv >> 1) * 64, mh0 = (wv & 1) * 64;
  f32x4 acc1[4][4] = {};
#pragma unroll
  for (int kt = 0; kt < 2; ++kt) {
    bf16x8 wa[4], kb[4];
#pragma unroll
    for (int i = 0; i < 4; ++i)
      wa[i] = *(const bf16x8*)&W1p[(c0 + i * 16 + lrow) * 72 + kt * 32 + lq * 8];
#pragma unroll
    for (int j = 0; j < 4; ++j)
      kb[j] = *(const bf16x8*)&As[(mh0 + j * 16 + lrow) * 72 + kt * 32 + lq * 8];
#pragma unroll
    for (int i = 0; i < 4; ++i)
#pragma unroll
      for (int j = 0; j < 4; ++j)
        acc1[i][j] = __builtin_amdgcn_mfma_f32_16x16x32_bf16(wa[i], kb[j], acc1[i][j], 0, 0, 0);
  }
  __syncthreads();   // As/W1p dead; hid overlays

  // ---- epilogue1: gelu -> hid[m][c] (4 contiguous c per lane) ----
#pragma unroll
  for (int i = 0; i < 4; ++i) {
    const int cc = c0 + i * 16 + lq * 4;
    float4 bv = *(const float4*)(b1 + cc);
#pragma unroll
    for (int j = 0; j < 4; ++j) {
      const int m = mh0 + j * 16 + lrow;
      float x0 = acc1[i][j][0] + bv.x, x1 = acc1[i][j][1] + bv.y;
      float x2 = acc1[i][j][2] + bv.z, x3 = acc1[i][j][3] + bv.w;
      ushort4 w;
      w.x = f2bf(0.5f * x0 * (1.f + erff(x0 * 0.7071067811865475f)));
      w.y = f2bf(0.5f * x1 * (1.f + erff(x1 * 0.7071067811865475f)));
      w.z = f2bf(0.5f * x2 * (1.f + erff(x2 * 0.7071067811865475f)));
      w.w = f2bf(0.5f * x3 * (1.f + erff(x3 * 0.7071067811865475f)));
      *(ushort4*)&hid[m * 136 + cc] = w;
    }
  }
  __syncthreads();

  // ---- pass 2: C[m][d] = hid x W2 (A=hid -> rows m, B=W2 -> cols d) ----
  const int d0 = (wv >> 1) * 32, mh2 = (wv & 1) * 64;
  f32x4 acc2[4][2] = {};   // [m-tile j][d-tile i]
#pragma unroll
  for (int kt = 0; kt < 4; ++kt) {
    bf16x8 wa[2], hb[4];
#pragma unroll
    for (int i = 0; i < 2; ++i)
      wa[i] = *(const bf16x8*)&W2p[(d0 + i * 16 + lrow) * 136 + kt * 32 + lq * 8];
#pragma unroll
    for (int j = 0; j < 4; ++j)
      hb[j] = *(const bf16x8*)&hid[(mh2 + j * 16 + lrow) * 136 + kt * 32 + lq * 8];
#pragma unroll
    for (int j = 0; j < 4; ++j)
#pragma unroll
      for (int i = 0; i < 2; ++i)
        acc2[j][i] = __builtin_amdgcn_mfma_f32_16x16x32_bf16(hb[j], wa[i], acc2[j][i], 0, 0, 0);
  }
  __syncthreads();   // all waves done reading hid; LT2 overlays

  // ---- epilogue2: elu+1, /M -> LT2[d][m] (vector writes, lane holds 4 m) ----
#pragma unroll
  for (int i = 0; i < 2; ++i) {
    const int d = d0 + i * 16 + lrow;
    const float bd = b2[d];
#pragma unroll
    for (int j = 0; j < 4; ++j) {
      const int ml = mh2 + j * 16 + lq * 4;
      ushort4 w;
#pragma unroll
      for (int p = 0; p < 4; ++p) {
        float v = acc2[j][i][p] + bd;
        v = ((v > 0.f) ? (v + 1.f) : __expf(v)) * invM;
        ((u16*)&w)[p] = f2bf(v);
      }
      *(ushort4*)&LT2[d * 136 + ml] = w;
    }
  }
  __syncthreads();
  // coalesced copy-out: 1024 chunks of 8 m
#pragma unroll
  for (int it = 0; it < 4; ++it) {
    const int c = it * 256 + tid;
    const int d = c >> 4, mq = (c & 15) * 8;
    uint4 v = *(const uint4*)&LT2[d * 136 + mq];
    *(uint4*)(kaT + ((long)bh * 64 + d) * 4096 + m0 + mq) = v;
  }
}

// ---------------------------------------------------------------------------
// kv GEMM: D[d][e] = sum_m kaT[bh][d][m] * vT[bh][e][m]  (split-K 16)
// ksum[d] via all-ones B fragment. Partials fp32.
// ---------------------------------------------------------------------------
__global__ __launch_bounds__(256)
void kv_gemm(const u16* __restrict__ kaT, const u16* __restrict__ vT,
             float* __restrict__ kvp, float* __restrict__ ksp)
{
  const int sp = blockIdx.x;   // 0..15
  const int bh = blockIdx.y;   // 0..31
  __shared__ u16 SB[16384];
  u16* As = SB;
  u16* Bs = SB + 8192;
  const int tid = threadIdx.x, wv = tid >> 6, lane = tid & 63;
  const int lrow = lane & 15, lq = lane >> 4;
  f32x4 acc[4][4] = {};
  f32x4 accs[4] = {};
  bf16x8 ones;
#pragma unroll
  for (int z = 0; z < 8; ++z) ones[z] = (__bf16)1.0f;
  const long base = (long)bh * 64 * 4096;

  for (int ph = 0; ph < 2; ++ph) {
    const int m0 = sp * 256 + ph * 128;
#pragma unroll
    for (int i = 0; i < 4; ++i) {
      const int s = (wv * 4 + i) * 64 + lane;
      const int chunk = s >> 8, row = (s >> 2) & 63, part = s & 3;
      const long g = base + (long)row * 4096 + m0 + chunk * 32 + part * 8;
      async16(kaT + g, &As[(wv * 4 + i) * 512]);
      async16(vT + g, &Bs[(wv * 4 + i) * 512]);
    }
    __syncthreads();
    bf16x8 af[4], bfr[4];
#pragma unroll
    for (int i = 0; i < 4; ++i)
      af[i] = *(const bf16x8*)&As[wv * 2048 + (i * 16 + lrow) * 32 + lq * 8];
#pragma unroll
    for (int j = 0; j < 4; ++j)
      bfr[j] = *(const bf16x8*)&Bs[wv * 2048 + (j * 16 + lrow) * 32 + lq * 8];
#pragma unroll
    for (int i = 0; i < 4; ++i) {
#pragma unroll
      for (int j = 0; j < 4; ++j)
        acc[i][j] = __builtin_amdgcn_mfma_f32_16x16x32_bf16(af[i], bfr[j], acc[i][j], 0, 0, 0);
      accs[i] = __builtin_amdgcn_mfma_f32_16x16x32_bf16(af[i], ones, accs[i], 0, 0, 0);
    }
    __syncthreads();
  }

  float* red = (float*)SB;        // red[e][68] + ksr[64]
  float* ksr = red + 64 * 68;
  for (int w = 0; w < 4; ++w) {
    __syncthreads();
    if (wv == w) {
#pragma unroll
      for (int i = 0; i < 4; ++i) {
#pragma unroll
        for (int j = 0; j < 4; ++j) {
          const int e = j * 16 + lrow, dd = i * 16 + lq * 4;
          float* p = &red[e * 68 + dd];
          if (w == 0) { p[0] = acc[i][j][0]; p[1] = acc[i][j][1]; p[2] = acc[i][j][2]; p[3] = acc[i][j][3]; }
          else        { p[0] += acc[i][j][0]; p[1] += acc[i][j][1]; p[2] += acc[i][j][2]; p[3] += acc[i][j][3]; }
        }
        if (lrow == 0) {
          const int dd = i * 16 + lq * 4;
#pragma unroll
          for (int p2 = 0; p2 < 4; ++p2) {
            if (w == 0) ksr[dd + p2] = accs[i][p2];
            else        ksr[dd + p2] += accs[i][p2];
          }
        }
      }
    }
  }
  __syncthreads();
  float* kvo = kvp + ((long)sp * 32 + bh) * 4096;
  for (int s = tid; s < 4096; s += 256) kvo[s] = red[(s >> 6) * 68 + (s & 63)];
  if (tid < 64) ksp[(sp * 32 + bh) * 64 + tid] = ksr[tid];
}

__global__ __launch_bounds__(256)
void kv_reduce(const float* __restrict__ kvp, const float* __restrict__ ksp,
               u16* __restrict__ kvT, u16* __restrict__ ksumT)
{
  const int bh = blockIdx.x;
  const int t = threadIdx.x;
  for (int s = t; s < 4096; s += 256) {
    float v = 0.f;
#pragma unroll
    for (int sp = 0; sp < 16; ++sp) v += kvp[((long)sp * 32 + bh) * 4096 + s];
    kvT[(long)bh * 4096 + s] = f2bf(v);
  }
  if (t < 64) {
    float v = 0.f;
#pragma unroll
    for (int sp = 0; sp < 16; ++sp) v += ksp[(sp * 32 + bh) * 64 + t];
    ksumT[bh * 64 + t] = f2bf(v);
  }
}

// ---------------------------------------------------------------------------
// attn MFMA: per (bh, 256 n): out[n][e] = (q@kv) / max(q@ksum,1e-6)
// ---------------------------------------------------------------------------
__global__ __launch_bounds__(256)
void attn_mfma(const u16* __restrict__ q, const u16* __restrict__ kvT,
               const u16* __restrict__ ksumT, u16* __restrict__ attn)
{
  __shared__ u16 SB[17408];
  const int tid = threadIdx.x, wv = tid >> 6, lane = tid & 63;
  const int lrow = lane & 15, lq = lane >> 4;
  const int n0 = blockIdx.x * 256;
  const int bh = blockIdx.y, b = bh >> 3, h = bh & 7;
  u16* As = SB;

#pragma unroll
  for (int half = 0; half < 2; ++half)
#pragma unroll
    for (int i = 0; i < 4; ++i) {
      const int s = (wv * 4 + i) * 64 + lane;
      async16(q + ((long)(b * 4096 + n0 + (s >> 2))) * 512 + h * 64 + half * 32 + (s & 3) * 8,
              &As[half * 8192 + (wv * 4 + i) * 512]);
    }
  bf16x8 bfr[2][4], ks[2];
#pragma unroll
  for (int half = 0; half < 2; ++half) {
#pragma unroll
    for (int j = 0; j < 4; ++j)
      bfr[half][j] = *(const bf16x8*)(kvT + ((long)bh * 64 + j * 16 + lrow) * 64 + half * 32 + lq * 8);
    ks[half] = *(const bf16x8*)(ksumT + bh * 64 + half * 32 + lq * 8);
  }
  __syncthreads();

  f32x4 acc[4][4] = {};
  f32x4 accd[4] = {};
#pragma unroll
  for (int half = 0; half < 2; ++half) {
    bf16x8 af[4];
#pragma unroll
    for (int i = 0; i < 4; ++i)
      af[i] = *(const bf16x8*)&As[half * 8192 + (wv * 64 + i * 16 + lrow) * 32 + lq * 8];
#pragma unroll
    for (int i = 0; i < 4; ++i) {
#pragma unroll
      for (int j = 0; j < 4; ++j)
        acc[i][j] = __builtin_amdgcn_mfma_f32_16x16x32_bf16(af[i], bfr[half][j], acc[i][j], 0, 0, 0);
      accd[i] = __builtin_amdgcn_mfma_f32_16x16x32_bf16(af[i], ks[half], accd[i], 0, 0, 0);
    }
  }
  __syncthreads();

  u16* LT = SB;   // LT[wv][64 e][68 n]
#pragma unroll
  for (int i = 0; i < 4; ++i) {
    float dinv[4];
#pragma unroll
    for (int p = 0; p < 4; ++p) dinv[p] = 1.f / fmaxf(accd[i][p], 1e-6f);
#pragma unroll
    for (int j = 0; j < 4; ++j) {
      const int e = j * 16 + lrow;
      const int nl0 = i * 16 + lq * 4;
      ushort4 w;
      float x0 = acc[i][j][0] * dinv[0], x1 = acc[i][j][1] * dinv[1];
      float x2 = acc[i][j][2] * dinv[2], x3 = acc[i][j][3] * dinv[3];
      if (!(x0 == x0)) x0 = 0.f;
      if (!(x1 == x1)) x1 = 0.f;
      if (!(x2 == x2)) x2 = 0.f;
      if (!(x3 == x3)) x3 = 0.f;
      w.x = f2bf(fminf(65000.f, fmaxf(-65000.f, x0)));
      w.y = f2bf(fminf(65000.f, fmaxf(-65000.f, x1)));
      w.z = f2bf(fminf(65000.f, fmaxf(-65000.f, x2)));
      w.w = f2bf(fminf(65000.f, fmaxf(-65000.f, x3)));
      *(ushort4*)&LT[wv * 4352 + e * 68 + nl0] = w;
    }
  }
  __syncthreads();
#pragma unroll
  for (int it = 0; it < 8; ++it) {
    const int c = it * 256 + tid;
    const int n = c & 255, ec = c >> 8;
    const int wr2 = n >> 6, nl = n & 63;
    ushort4 w0, w1;
    w0.x = LT[wr2 * 4352 + (ec * 8 + 0) * 68 + nl];
    w0.y = LT[wr2 * 4352 + (ec * 8 + 1) * 68 + nl];
    w0.z = LT[wr2 * 4352 + (ec * 8 + 2) * 68 + nl];
    w0.w = LT[wr2 * 4352 + (ec * 8 + 3) * 68 + nl];
    w1.x = LT[wr2 * 4352 + (ec * 8 + 4) * 68 + nl];
    w1.y = LT[wr2 * 4352 + (ec * 8 + 5) * 68 + nl];
    w1.z = LT[wr2 * 4352 + (ec * 8 + 6) * 68 + nl];
    w1.w = LT[wr2 * 4352 + (ec * 8 + 7) * 68 + nl];
    u16* dst = attn + ((long)(b * 4096 + n0 + n)) * 512 + h * 64 + ec * 8;
    *(ushort4*)dst = w0;
    *(ushort4*)(dst + 4) = w1;
  }
}

// ---------------------------------------------------------------------------
static constexpr long U = 8388608;   // elems of one [4,4096,512] tensor

extern "C" void kernel_launch(void* const* d_in, const int* in_sizes, int n_in,
                              void* d_out, int out_size, void* d_ws, size_t ws_size,
                              hipStream_t stream)
{
  const float* query = (const float*)d_in[0];
  const float* key   = (const float*)d_in[1];
  const float* value = (const float*)d_in[2];
  const float* Wq = (const float*)d_in[3];
  const float* bq = (const float*)d_in[4];
  const float* Wk = (const float*)d_in[5];
  const float* bk = (const float*)d_in[6];
  const float* Wv = (const float*)d_in[7];
  const float* bv = (const float*)d_in[8];
  const float* W1 = (const float*)d_in[9];
  const float* b1 = (const float*)d_in[10];
  const float* W2 = (const float*)d_in[11];
  const float* b2 = (const float*)d_in[12];
  const float* Wo = (const float*)d_in[13];
  const float* bo = (const float*)d_in[14];

  u16* wsh = (u16*)d_ws;
  u16* qact = wsh;           // [16384,512] bf16
  u16* kact = wsh + U;
  u16* vT   = wsh + 2 * U;   // vT[b][h][e][m]
  u16* kaT  = wsh + 3 * U;   // [32][64][4096]
  u16* attn = wsh + 4 * U;

  float* fp  = (float*)(wsh + 5 * U);
  float* kvp = fp;                     // 16*32*4096
  float* ksp = fp + 2097152;           // 16*32*64
  u16* kvTg   = (u16*)(fp + 2129920);  // 32*4096
  u16* ksumTg = kvTg + 131072;         // 32*64
  u16* wtb = ksumTg + 2048;
  u16* WqT = wtb;                      // [512,512]
  u16* WkT = wtb + 262144;
  u16* WvT = wtb + 524288;
  u16* WoT = wtb + 786432;
  u16* W1T = wtb + 1048576;            // [128,64]
  u16* W2T = wtb + 1056768;            // [64,128]

  dim3 blk(256);
  const float invM = 1.f / 4096.f;

  TArgs ta;
  ta.src[0] = Wq; ta.dst[0] = WqT; ta.K[0] = 512; ta.N[0] = 512;
  ta.src[1] = Wk; ta.dst[1] = WkT; ta.K[1] = 512; ta.N[1] = 512;
  ta.src[2] = Wv; ta.dst[2] = WvT; ta.K[2] = 512; ta.N[2] = 512;
  ta.src[3] = Wo; ta.dst[3] = WoT; ta.K[3] = 512; ta.N[3] = 512;
  ta.src[4] = W1; ta.dst[4] = W1T; ta.K[4] = 64;  ta.N[4] = 128;
  ta.src[5] = W2; ta.dst[5] = W2T; ta.K[5] = 128; ta.N[5] = 64;
  transpose_w<<<dim3(8, 8, 6), blk, 0, stream>>>(ta);

  // projections straight from fp32 inputs (cvt during staging)
  gemm_bf16<128,128,512,2,2,ACT_ELU1,1,OM_ROW,1><<<dim3(4,128), blk, 0, stream>>>(query, WqT, bq, qact, 512, 1.f);
  gemm_bf16<128,128,512,2,2,ACT_ELU1,1,OM_ROW,1><<<dim3(4,128), blk, 0, stream>>>(key,   WkT, bk, kact, 512, 1.f);
  gemm_bf16<128,128,512,2,2,ACT_ID,  1,OM_VT, 1><<<dim3(4,128), blk, 0, stream>>>(value, WvT, bv, vT,   512, 1.f);
  // fused rank-expansion MLP -> kaT
  mlp_fused<<<dim3(32,32), blk, 0, stream>>>(kact, W1T, W2T, b1, b2, kaT, invM);
  // kv context + ksum (MFMA split-K 16) then reduce to bf16
  kv_gemm<<<dim3(16,32), blk, 0, stream>>>(kaT, vT, kvp, ksp);
  kv_reduce<<<dim3(32), blk, 0, stream>>>(kvp, ksp, kvTg, ksumTg);
  // attention output
  attn_mfma<<<dim3(16,32), blk, 0, stream>>>(qact, kvTg, ksumTg, attn);
  // final projection -> d_out fp32
  gemm_bf16<128,128,512,2,2,ACT_ID,0,OM_ROW,0><<<dim3(4,128), blk, 0, stream>>>(attn, WoT, bo, (float*)d_out, 512, 1.f);
}

// Round 7
// 276.871 us; speedup vs baseline: 1.1048x; 1.1048x over previous
//
#include <hip/hip_runtime.h>
#include <hip/hip_bf16.h>
#include <cmath>

#define DEV __device__ __forceinline__

typedef __bf16 bf16x8 __attribute__((ext_vector_type(8)));
typedef float f32x4 __attribute__((ext_vector_type(4)));
typedef unsigned int u32;
typedef unsigned short u16;

DEV u16 f2bf(float f) {
  union { float f; u32 u; } v;
  v.f = f;
  u32 u = v.u;
  u += 0x7fffu + ((u >> 16) & 1u);   // RNE
  return (u16)(u >> 16);
}
// packed RNE cvt: 2 f32 -> u32 of 2 bf16 (v_cvt_pk_bf16_f32 on gfx950)
DEV u32 pk2(float a, float b) {
  union { __hip_bfloat162 h2; u32 u; } v;
  v.h2 = __float22bfloat162_rn(float2{a, b});
  return v.u;
}

// async global->LDS, 16B per lane; LDS dst is wave-uniform base + lane*16
DEV void async16(const void* g, void* l) {
  __builtin_amdgcn_global_load_lds((const __attribute__((address_space(1))) u32*)g,
                                   (__attribute__((address_space(3))) u32*)l, 16, 0, 0);
}

// ---------------------------------------------------------------------------
// fused QKV projection GEMM. grid (128 row, 4 col, 3 tensor); x=row fastest so
// the 4 col-blocks of a row land on the same XCD (flat%8 = row%8) -> A tile is
// fetched from HBM once, re-served from that XCD's L2.
// A fp32 staged raw via async16 (XOR part-swizzle); frags cvt with pk2.
// z=0: q=elu+1->qact row-major; z=1: k=elu+1->kact; z=2: v=id->vT[b][h][e][m].
// ---------------------------------------------------------------------------
__global__ __launch_bounds__(256)
void qkv_gemm(const float* __restrict__ qin, const float* __restrict__ kin,
              const float* __restrict__ vin, const u16* __restrict__ WqT,
              const u16* __restrict__ WkT, const u16* __restrict__ WvT,
              const float* __restrict__ bq, const float* __restrict__ bk,
              const float* __restrict__ bv, u16* __restrict__ qact,
              u16* __restrict__ kact, u16* __restrict__ vT)
{
  __shared__ __align__(16) u16 SB[18432];  // staging 12288 u16; OM_VT bounce 18432
  float* Asf = (float*)SB;                  // A raw fp32 [128 rows][32 k] = 8192 u16
  u16* Bs = SB + 8192;                      // B bf16 [128 c][32 k] = 4096 u16

  const int z = blockIdx.z;
  const float* Af = z == 0 ? qin : z == 1 ? kin : vin;
  const u16* Bt = z == 0 ? WqT : z == 1 ? WkT : WvT;
  const float* bias = z == 0 ? bq : z == 1 ? bk : bv;

  const int tid = threadIdx.x, wv = tid >> 6, lane = tid & 63;
  const int wr = wv >> 1, wc = wv & 1;
  const int lrow = lane & 15, lq = lane >> 4;
  const long r0 = (long)blockIdx.x * 128;
  const int c0 = blockIdx.y * 128;

  f32x4 acc[4][4] = {};

  for (int kt = 0; kt < 512; kt += 32) {
    // A: 1024 slots of 16B (4 f32); row = s>>3, part = s&7, XOR-swizzled
#pragma unroll
    for (int i = 0; i < 4; ++i) {
      const int s = (wv * 4 + i) * 64 + lane;
      const int row = s >> 3, p = s & 7;
      const int gp = p ^ (row & 7);
      async16(Af + (r0 + row) * 512 + kt + gp * 4, (char*)SB + (wv * 4 + i) * 1024);
    }
#pragma unroll
    for (int i = 0; i < 2; ++i) {
      const int s = (wv * 2 + i) * 64 + lane;
      async16(Bt + ((long)c0 + (s >> 2)) * 512 + kt + (s & 3) * 8,
              &Bs[(wv * 2 + i) * 512]);
    }
    __syncthreads();
    bf16x8 af[4], bfr[4];
#pragma unroll
    for (int i = 0; i < 4; ++i) {
      const int r = wr * 64 + i * 16 + lrow;
      const int r7 = r & 7, P0 = lq * 2;
      float4 lo = *(const float4*)&Asf[r * 32 + (P0 ^ r7) * 4];
      float4 hi = *(const float4*)&Asf[r * 32 + ((P0 + 1) ^ r7) * 4];
      union { u32 q[4]; bf16x8 v; } pk;
      pk.q[0] = pk2(lo.x, lo.y); pk.q[1] = pk2(lo.z, lo.w);
      pk.q[2] = pk2(hi.x, hi.y); pk.q[3] = pk2(hi.z, hi.w);
      af[i] = pk.v;
    }
#pragma unroll
    for (int j = 0; j < 4; ++j)
      bfr[j] = *(const bf16x8*)&Bs[(wc * 64 + j * 16 + lrow) * 32 + lq * 8];
#pragma unroll
    for (int i = 0; i < 4; ++i)
#pragma unroll
      for (int j = 0; j < 4; ++j)
        acc[i][j] = __builtin_amdgcn_mfma_f32_16x16x32_bf16(af[i], bfr[j], acc[i][j], 0, 0, 0);
    __syncthreads();
  }

  if (z < 2) {
    // elu+1, row-major bf16
    u16* Y = z == 0 ? qact : kact;
#pragma unroll
    for (int i = 0; i < 4; ++i) {
#pragma unroll
      for (int j = 0; j < 4; ++j) {
        const int col = c0 + wc * 64 + j * 16 + lrow;
        const float bvv = bias[col];
#pragma unroll
        for (int p = 0; p < 4; ++p) {
          float o = acc[i][j][p] + bvv;
          o = (o > 0.f) ? (o + 1.f) : __expf(o);
          const long row = r0 + wr * 64 + i * 16 + lq * 4 + p;
          Y[row * 512 + col] = f2bf(o);
        }
      }
    }
  } else {
    // identity -> vT[b][h][e][m] via per-wave LDS bounce (64e x 64m, pad 72)
    u16* LTv = SB + wv * 4608;
#pragma unroll
    for (int i = 0; i < 4; ++i) {
#pragma unroll
      for (int j = 0; j < 4; ++j) {
        const int col = c0 + wc * 64 + j * 16 + lrow;
        const float bvv = bias[col];
        ushort4 w;
        w.x = f2bf(acc[i][j][0] + bvv);
        w.y = f2bf(acc[i][j][1] + bvv);
        w.z = f2bf(acc[i][j][2] + bvv);
        w.w = f2bf(acc[i][j][3] + bvv);
        *(ushort4*)&LTv[(j * 16 + lrow) * 72 + i * 16 + lq * 4] = w;
      }
    }
    const int b = (int)(r0 >> 12);
    const int h = (c0 + wc * 64) >> 6;
    const int mg0 = (int)(r0 & 4095) + wr * 64;
#pragma unroll
    for (int ps = 0; ps < 8; ++ps) {
      const int e = ps * 8 + (lane >> 3);
      const int mq = (lane & 7) * 8;
      uint4 v = *(const uint4*)&LTv[e * 72 + mq];
      *(uint4*)(vT + (((long)b * 8 + h) * 64 + e) * 4096 + mg0 + mq) = v;
    }
  }
}

// ---------------------------------------------------------------------------
// final projection: d_out[row][col] = attn(bf16) @ WoT + bo, fp32 out.
// grid (128 row, 4 col) — same XCD row-swizzle.
// ---------------------------------------------------------------------------
__global__ __launch_bounds__(256)
void out_gemm(const u16* __restrict__ A, const u16* __restrict__ Bt,
              const float* __restrict__ bias, float* __restrict__ Y)
{
  __shared__ __align__(16) u16 SB[8192];
  u16* As = SB;
  u16* Bs = SB + 4096;
  const int tid = threadIdx.x, wv = tid >> 6, lane = tid & 63;
  const int wr = wv >> 1, wc = wv & 1;
  const int lrow = lane & 15, lq = lane >> 4;
  const long r0 = (long)blockIdx.x * 128;
  const int c0 = blockIdx.y * 128;

  f32x4 acc[4][4] = {};
  for (int kt = 0; kt < 512; kt += 32) {
#pragma unroll
    for (int i = 0; i < 2; ++i) {
      const int s = (wv * 2 + i) * 64 + lane;
      async16(A + (r0 + (s >> 2)) * 512 + kt + (s & 3) * 8, &As[(wv * 2 + i) * 512]);
      async16(Bt + ((long)c0 + (s >> 2)) * 512 + kt + (s & 3) * 8, &Bs[(wv * 2 + i) * 512]);
    }
    __syncthreads();
    bf16x8 af[4], bfr[4];
#pragma unroll
    for (int i = 0; i < 4; ++i)
      af[i] = *(const bf16x8*)&As[(wr * 64 + i * 16 + lrow) * 32 + lq * 8];
#pragma unroll
    for (int j = 0; j < 4; ++j)
      bfr[j] = *(const bf16x8*)&Bs[(wc * 64 + j * 16 + lrow) * 32 + lq * 8];
#pragma unroll
    for (int i = 0; i < 4; ++i)
#pragma unroll
      for (int j = 0; j < 4; ++j)
        acc[i][j] = __builtin_amdgcn_mfma_f32_16x16x32_bf16(af[i], bfr[j], acc[i][j], 0, 0, 0);
    __syncthreads();
  }
#pragma unroll
  for (int i = 0; i < 4; ++i) {
#pragma unroll
    for (int j = 0; j < 4; ++j) {
      const int col = c0 + wc * 64 + j * 16 + lrow;
      const float bv = bias[col];
#pragma unroll
      for (int p = 0; p < 4; ++p) {
        const long row = r0 + wr * 64 + i * 16 + lq * 4 + p;
        Y[row * 512 + col] = acc[i][j][p] + bv;
      }
    }
  }
}

// ---------------------------------------------------------------------------
// weight transpose+convert: W [K,N] fp32 -> Wt [N,K] bf16
// ---------------------------------------------------------------------------
struct TArgs {
  const float* src[6];
  u16* dst[6];
  int K[6];
  int N[6];
};
__global__ __launch_bounds__(256)
void transpose_w(TArgs a)
{
  const int m = blockIdx.z;
  const int K = a.K[m], N = a.N[m];
  const int kt = blockIdx.y * 64, nt = blockIdx.x * 64;
  if (kt >= K || nt >= N) return;
  const float* src = a.src[m];
  u16* dst = a.dst[m];
  __shared__ u16 t[64][72];
  const int tx = threadIdx.x & 15, ty = threadIdx.x >> 4;
#pragma unroll
  for (int rr = 0; rr < 64; rr += 16) {
    const int k = kt + ty + rr;
    float4 v = *(const float4*)(src + (long)k * N + nt + tx * 4);
    t[tx * 4 + 0][ty + rr] = f2bf(v.x);
    t[tx * 4 + 1][ty + rr] = f2bf(v.y);
    t[tx * 4 + 2][ty + rr] = f2bf(v.z);
    t[tx * 4 + 3][ty + rr] = f2bf(v.w);
  }
  __syncthreads();
#pragma unroll
  for (int it = 0; it < 2; ++it) {
    const int s = threadIdx.x + it * 256;
    const int r = s >> 3, c = (s & 7) * 8;
    ushort4 u0 = *(ushort4*)&t[r][c];
    ushort4 u1 = *(ushort4*)&t[r][c + 4];
    *(ushort4*)(dst + (long)(nt + r) * K + kt + c) = u0;
    *(ushort4*)(dst + (long)(nt + r) * K + kt + c + 4) = u1;
  }
}

// ---------------------------------------------------------------------------
// fused MLP (unchanged from R6): kaT[bh][d][m] = (elu(gelu(k@W1+b1)@W2+b2)+1)/M
// ---------------------------------------------------------------------------
__global__ __launch_bounds__(256)
void mlp_fused(const u16* __restrict__ kact, const u16* __restrict__ W1T,
               const u16* __restrict__ W2T, const float* __restrict__ b1,
               const float* __restrict__ b2, u16* __restrict__ kaT, float invM)
{
  __shared__ __align__(16) u16 SB[27136];
  u16* As  = SB;            // [128 m][72]
  u16* W1p = SB + 9216;     // [128 c][72]
  u16* W2p = SB + 18432;    // [64 d][136]
  u16* hid = SB;            // [128 m][136] overlay
  u16* LT2 = SB;            // [64 d][136] overlay

  const int tid = threadIdx.x, wv = tid >> 6, lane = tid & 63;
  const int lrow = lane & 15, lq = lane >> 4;
  const int bh = blockIdx.y, b = bh >> 3, h = bh & 7;
  const int m0 = blockIdx.x * 128;
  const long kbase = ((long)b * 4096 + m0) * 512 + h * 64;

#pragma unroll
  for (int i = 0; i < 4; ++i) {
    const int c = i * 256 + tid;
    const int row = c >> 3, p = c & 7;
    uint4 v = *(const uint4*)(kact + kbase + (long)row * 512 + p * 8);
    *(uint4*)&As[row * 72 + p * 8] = v;
  }
#pragma unroll
  for (int i = 0; i < 4; ++i) {
    const int c = i * 256 + tid;
    const int row = c >> 3, p = c & 7;
    uint4 v = *(const uint4*)(W1T + c * 8);
    *(uint4*)&W1p[row * 72 + p * 8] = v;
  }
#pragma unroll
  for (int i = 0; i < 4; ++i) {
    const int c = i * 256 + tid;
    const int row = c >> 4, p = c & 15;
    uint4 v = *(const uint4*)(W2T + c * 8);
    *(uint4*)&W2p[row * 136 + p * 8] = v;
  }
  __syncthreads();

  const int c0 = (wv >> 1) * 64, mh0 = (wv & 1) * 64;
  f32x4 acc1[4][4] = {};
#pragma unroll
  for (int kt = 0; kt < 2; ++kt) {
    bf16x8 wa[4], kb[4];
#pragma unroll
    for (int i = 0; i < 4; ++i)
      wa[i] = *(const bf16x8*)&W1p[(c0 + i * 16 + lrow) * 72 + kt * 32 + lq * 8];
#pragma unroll
    for (int j = 0; j < 4; ++j)
      kb[j] = *(const bf16x8*)&As[(mh0 + j * 16 + lrow) * 72 + kt * 32 + lq * 8];
#pragma unroll
    for (int i = 0; i < 4; ++i)
#pragma unroll
      for (int j = 0; j < 4; ++j)
        acc1[i][j] = __builtin_amdgcn_mfma_f32_16x16x32_bf16(wa[i], kb[j], acc1[i][j], 0, 0, 0);
  }
  __syncthreads();

#pragma unroll
  for (int i = 0; i < 4; ++i) {
    const int cc = c0 + i * 16 + lq * 4;
    float4 bv = *(const float4*)(b1 + cc);
#pragma unroll
    for (int j = 0; j < 4; ++j) {
      const int m = mh0 + j * 16 + lrow;
      float x0 = acc1[i][j][0] + bv.x, x1 = acc1[i][j][1] + bv.y;
      float x2 = acc1[i][j][2] + bv.z, x3 = acc1[i][j][3] + bv.w;
      ushort4 w;
      w.x = f2bf(0.5f * x0 * (1.f + erff(x0 * 0.7071067811865475f)));
      w.y = f2bf(0.5f * x1 * (1.f + erff(x1 * 0.7071067811865475f)));
      w.z = f2bf(0.5f * x2 * (1.f + erff(x2 * 0.7071067811865475f)));
      w.w = f2bf(0.5f * x3 * (1.f + erff(x3 * 0.7071067811865475f)));
      *(ushort4*)&hid[m * 136 + cc] = w;
    }
  }
  __syncthreads();

  const int d0 = (wv >> 1) * 32, mh2 = (wv & 1) * 64;
  f32x4 acc2[4][2] = {};
#pragma unroll
  for (int kt = 0; kt < 4; ++kt) {
    bf16x8 wa[2], hb[4];
#pragma unroll
    for (int i = 0; i < 2; ++i)
      wa[i] = *(const bf16x8*)&W2p[(d0 + i * 16 + lrow) * 136 + kt * 32 + lq * 8];
#pragma unroll
    for (int j = 0; j < 4; ++j)
      hb[j] = *(const bf16x8*)&hid[(mh2 + j * 16 + lrow) * 136 + kt * 32 + lq * 8];
#pragma unroll
    for (int j = 0; j < 4; ++j)
#pragma unroll
      for (int i = 0; i < 2; ++i)
        acc2[j][i] = __builtin_amdgcn_mfma_f32_16x16x32_bf16(hb[j], wa[i], acc2[j][i], 0, 0, 0);
  }
  __syncthreads();

#pragma unroll
  for (int i = 0; i < 2; ++i) {
    const int d = d0 + i * 16 + lrow;
    const float bd = b2[d];
#pragma unroll
    for (int j = 0; j < 4; ++j) {
      const int ml = mh2 + j * 16 + lq * 4;
      ushort4 w;
#pragma unroll
      for (int p = 0; p < 4; ++p) {
        float v = acc2[j][i][p] + bd;
        v = ((v > 0.f) ? (v + 1.f) : __expf(v)) * invM;
        ((u16*)&w)[p] = f2bf(v);
      }
      *(ushort4*)&LT2[d * 136 + ml] = w;
    }
  }
  __syncthreads();
#pragma unroll
  for (int it = 0; it < 4; ++it) {
    const int c = it * 256 + tid;
    const int d = c >> 4, mq = (c & 15) * 8;
    uint4 v = *(const uint4*)&LT2[d * 136 + mq];
    *(uint4*)(kaT + ((long)bh * 64 + d) * 4096 + m0 + mq) = v;
  }
}

// ---------------------------------------------------------------------------
// kv GEMM (unchanged): D[d][e] = sum_m kaT*vT, split-K 16, + ksum via ones.
// ---------------------------------------------------------------------------
__global__ __launch_bounds__(256)
void kv_gemm(const u16* __restrict__ kaT, const u16* __restrict__ vT,
             float* __restrict__ kvp, float* __restrict__ ksp)
{
  const int sp = blockIdx.x;
  const int bh = blockIdx.y;
  __shared__ u16 SB[16384];
  u16* As = SB;
  u16* Bs = SB + 8192;
  const int tid = threadIdx.x, wv = tid >> 6, lane = tid & 63;
  const int lrow = lane & 15, lq = lane >> 4;
  f32x4 acc[4][4] = {};
  f32x4 accs[4] = {};
  bf16x8 ones;
#pragma unroll
  for (int z = 0; z < 8; ++z) ones[z] = (__bf16)1.0f;
  const long base = (long)bh * 64 * 4096;

  for (int ph = 0; ph < 2; ++ph) {
    const int m0 = sp * 256 + ph * 128;
#pragma unroll
    for (int i = 0; i < 4; ++i) {
      const int s = (wv * 4 + i) * 64 + lane;
      const int chunk = s >> 8, row = (s >> 2) & 63, part = s & 3;
      const long g = base + (long)row * 4096 + m0 + chunk * 32 + part * 8;
      async16(kaT + g, &As[(wv * 4 + i) * 512]);
      async16(vT + g, &Bs[(wv * 4 + i) * 512]);
    }
    __syncthreads();
    bf16x8 af[4], bfr[4];
#pragma unroll
    for (int i = 0; i < 4; ++i)
      af[i] = *(const bf16x8*)&As[wv * 2048 + (i * 16 + lrow) * 32 + lq * 8];
#pragma unroll
    for (int j = 0; j < 4; ++j)
      bfr[j] = *(const bf16x8*)&Bs[wv * 2048 + (j * 16 + lrow) * 32 + lq * 8];
#pragma unroll
    for (int i = 0; i < 4; ++i) {
#pragma unroll
      for (int j = 0; j < 4; ++j)
        acc[i][j] = __builtin_amdgcn_mfma_f32_16x16x32_bf16(af[i], bfr[j], acc[i][j], 0, 0, 0);
      accs[i] = __builtin_amdgcn_mfma_f32_16x16x32_bf16(af[i], ones, accs[i], 0, 0, 0);
    }
    __syncthreads();
  }

  float* red = (float*)SB;
  float* ksr = red + 64 * 68;
  for (int w = 0; w < 4; ++w) {
    __syncthreads();
    if (wv == w) {
#pragma unroll
      for (int i = 0; i < 4; ++i) {
#pragma unroll
        for (int j = 0; j < 4; ++j) {
          const int e = j * 16 + lrow, dd = i * 16 + lq * 4;
          float* p = &red[e * 68 + dd];
          if (w == 0) { p[0] = acc[i][j][0]; p[1] = acc[i][j][1]; p[2] = acc[i][j][2]; p[3] = acc[i][j][3]; }
          else        { p[0] += acc[i][j][0]; p[1] += acc[i][j][1]; p[2] += acc[i][j][2]; p[3] += acc[i][j][3]; }
        }
        if (lrow == 0) {
          const int dd = i * 16 + lq * 4;
#pragma unroll
          for (int p2 = 0; p2 < 4; ++p2) {
            if (w == 0) ksr[dd + p2] = accs[i][p2];
            else        ksr[dd + p2] += accs[i][p2];
          }
        }
      }
    }
  }
  __syncthreads();
  float* kvo = kvp + ((long)sp * 32 + bh) * 4096;
  for (int s = tid; s < 4096; s += 256) kvo[s] = red[(s >> 6) * 68 + (s & 63)];
  if (tid < 64) ksp[(sp * 32 + bh) * 64 + tid] = ksr[tid];
}

__global__ __launch_bounds__(256)
void kv_reduce(const float* __restrict__ kvp, const float* __restrict__ ksp,
               u16* __restrict__ kvT, u16* __restrict__ ksumT)
{
  const int bh = blockIdx.x;
  const int t = threadIdx.x;
  for (int s = t; s < 4096; s += 256) {
    float v = 0.f;
#pragma unroll
    for (int sp = 0; sp < 16; ++sp) v += kvp[((long)sp * 32 + bh) * 4096 + s];
    kvT[(long)bh * 4096 + s] = f2bf(v);
  }
  if (t < 64) {
    float v = 0.f;
#pragma unroll
    for (int sp = 0; sp < 16; ++sp) v += ksp[(sp * 32 + bh) * 64 + t];
    ksumT[bh * 64 + t] = f2bf(v);
  }
}

// ---------------------------------------------------------------------------
// attn MFMA (unchanged): out[n][e] = (q@kv) / max(q@ksum,1e-6)
// ---------------------------------------------------------------------------
__global__ __launch_bounds__(256)
void attn_mfma(const u16* __restrict__ q, const u16* __restrict__ kvT,
               const u16* __restrict__ ksumT, u16* __restrict__ attn)
{
  __shared__ u16 SB[17408];
  const int tid = threadIdx.x, wv = tid >> 6, lane = tid & 63;
  const int lrow = lane & 15, lq = lane >> 4;
  const int n0 = blockIdx.x * 256;
  const int bh = blockIdx.y, b = bh >> 3, h = bh & 7;
  u16* As = SB;

#pragma unroll
  for (int half = 0; half < 2; ++half)
#pragma unroll
    for (int i = 0; i < 4; ++i) {
      const int s = (wv * 4 + i) * 64 + lane;
      async16(q + ((long)(b * 4096 + n0 + (s >> 2))) * 512 + h * 64 + half * 32 + (s & 3) * 8,
              &As[half * 8192 + (wv * 4 + i) * 512]);
    }
  bf16x8 bfr[2][4], ks[2];
#pragma unroll
  for (int half = 0; half < 2; ++half) {
#pragma unroll
    for (int j = 0; j < 4; ++j)
      bfr[half][j] = *(const bf16x8*)(kvT + ((long)bh * 64 + j * 16 + lrow) * 64 + half * 32 + lq * 8);
    ks[half] = *(const bf16x8*)(ksumT + bh * 64 + half * 32 + lq * 8);
  }
  __syncthreads();

  f32x4 acc[4][4] = {};
  f32x4 accd[4] = {};
#pragma unroll
  for (int half = 0; half < 2; ++half) {
    bf16x8 af[4];
#pragma unroll
    for (int i = 0; i < 4; ++i)
      af[i] = *(const bf16x8*)&As[half * 8192 + (wv * 64 + i * 16 + lrow) * 32 + lq * 8];
#pragma unroll
    for (int i = 0; i < 4; ++i) {
#pragma unroll
      for (int j = 0; j < 4; ++j)
        acc[i][j] = __builtin_amdgcn_mfma_f32_16x16x32_bf16(af[i], bfr[half][j], acc[i][j], 0, 0, 0);
      accd[i] = __builtin_amdgcn_mfma_f32_16x16x32_bf16(af[i], ks[half], accd[i], 0, 0, 0);
    }
  }
  __syncthreads();

  u16* LT = SB;
#pragma unroll
  for (int i = 0; i < 4; ++i) {
    float dinv[4];
#pragma unroll
    for (int p = 0; p < 4; ++p) dinv[p] = 1.f / fmaxf(accd[i][p], 1e-6f);
#pragma unroll
    for (int j = 0; j < 4; ++j) {
      const int e = j * 16 + lrow;
      const int nl0 = i * 16 + lq * 4;
      ushort4 w;
      float x0 = acc[i][j][0] * dinv[0], x1 = acc[i][j][1] * dinv[1];
      float x2 = acc[i][j][2] * dinv[2], x3 = acc[i][j][3] * dinv[3];
      if (!(x0 == x0)) x0 = 0.f;
      if (!(x1 == x1)) x1 = 0.f;
      if (!(x2 == x2)) x2 = 0.f;
      if (!(x3 == x3)) x3 = 0.f;
      w.x = f2bf(fminf(65000.f, fmaxf(-65000.f, x0)));
      w.y = f2bf(fminf(65000.f, fmaxf(-65000.f, x1)));
      w.z = f2bf(fminf(65000.f, fmaxf(-65000.f, x2)));
      w.w = f2bf(fminf(65000.f, fmaxf(-65000.f, x3)));
      *(ushort4*)&LT[wv * 4352 + e * 68 + nl0] = w;
    }
  }
  __syncthreads();
#pragma unroll
  for (int it = 0; it < 8; ++it) {
    const int c = it * 256 + tid;
    const int n = c & 255, ec = c >> 8;
    const int wr2 = n >> 6, nl = n & 63;
    ushort4 w0, w1;
    w0.x = LT[wr2 * 4352 + (ec * 8 + 0) * 68 + nl];
    w0.y = LT[wr2 * 4352 + (ec * 8 + 1) * 68 + nl];
    w0.z = LT[wr2 * 4352 + (ec * 8 + 2) * 68 + nl];
    w0.w = LT[wr2 * 4352 + (ec * 8 + 3) * 68 + nl];
    w1.x = LT[wr2 * 4352 + (ec * 8 + 4) * 68 + nl];
    w1.y = LT[wr2 * 4352 + (ec * 8 + 5) * 68 + nl];
    w1.z = LT[wr2 * 4352 + (ec * 8 + 6) * 68 + nl];
    w1.w = LT[wr2 * 4352 + (ec * 8 + 7) * 68 + nl];
    u16* dst = attn + ((long)(b * 4096 + n0 + n)) * 512 + h * 64 + ec * 8;
    *(ushort4*)dst = w0;
    *(ushort4*)(dst + 4) = w1;
  }
}

// ---------------------------------------------------------------------------
static constexpr long U = 8388608;   // elems of one [4,4096,512] tensor

extern "C" void kernel_launch(void* const* d_in, const int* in_sizes, int n_in,
                              void* d_out, int out_size, void* d_ws, size_t ws_size,
                              hipStream_t stream)
{
  const float* query = (const float*)d_in[0];
  const float* key   = (const float*)d_in[1];
  const float* value = (const float*)d_in[2];
  const float* Wq = (const float*)d_in[3];
  const float* bq = (const float*)d_in[4];
  const float* Wk = (const float*)d_in[5];
  const float* bk = (const float*)d_in[6];
  const float* Wv = (const float*)d_in[7];
  const float* bv = (const float*)d_in[8];
  const float* W1 = (const float*)d_in[9];
  const float* b1 = (const float*)d_in[10];
  const float* W2 = (const float*)d_in[11];
  const float* b2 = (const float*)d_in[12];
  const float* Wo = (const float*)d_in[13];
  const float* bo = (const float*)d_in[14];

  u16* wsh = (u16*)d_ws;
  u16* qact = wsh;           // [16384,512] bf16
  u16* kact = wsh + U;
  u16* vT   = wsh + 2 * U;   // vT[b][h][e][m]
  u16* kaT  = wsh + 3 * U;   // [32][64][4096]
  u16* attn = wsh + 4 * U;

  float* fp  = (float*)(wsh + 5 * U);
  float* kvp = fp;                     // 16*32*4096
  float* ksp = fp + 2097152;           // 16*32*64
  u16* kvTg   = (u16*)(fp + 2129920);  // 32*4096
  u16* ksumTg = kvTg + 131072;         // 32*64
  u16* wtb = ksumTg + 2048;
  u16* WqT = wtb;                      // [512,512]
  u16* WkT = wtb + 262144;
  u16* WvT = wtb + 524288;
  u16* WoT = wtb + 786432;
  u16* W1T = wtb + 1048576;            // [128,64]
  u16* W2T = wtb + 1056768;            // [64,128]

  dim3 blk(256);
  const float invM = 1.f / 4096.f;

  TArgs ta;
  ta.src[0] = Wq; ta.dst[0] = WqT; ta.K[0] = 512; ta.N[0] = 512;
  ta.src[1] = Wk; ta.dst[1] = WkT; ta.K[1] = 512; ta.N[1] = 512;
  ta.src[2] = Wv; ta.dst[2] = WvT; ta.K[2] = 512; ta.N[2] = 512;
  ta.src[3] = Wo; ta.dst[3] = WoT; ta.K[3] = 512; ta.N[3] = 512;
  ta.src[4] = W1; ta.dst[4] = W1T; ta.K[4] = 64;  ta.N[4] = 128;
  ta.src[5] = W2; ta.dst[5] = W2T; ta.K[5] = 128; ta.N[5] = 64;
  transpose_w<<<dim3(8, 8, 6), blk, 0, stream>>>(ta);

  // fused q/k/v projections (row-major grid x for XCD L2 sharing of A)
  qkv_gemm<<<dim3(128, 4, 3), blk, 0, stream>>>(query, key, value, WqT, WkT, WvT,
                                                bq, bk, bv, qact, kact, vT);
  // fused rank-expansion MLP -> kaT
  mlp_fused<<<dim3(32, 32), blk, 0, stream>>>(kact, W1T, W2T, b1, b2, kaT, invM);
  // kv context + ksum (MFMA split-K 16) then reduce to bf16
  kv_gemm<<<dim3(16, 32), blk, 0, stream>>>(kaT, vT, kvp, ksp);
  kv_reduce<<<dim3(32), blk, 0, stream>>>(kvp, ksp, kvTg, ksumTg);
  // attention output
  attn_mfma<<<dim3(16, 32), blk, 0, stream>>>(qact, kvTg, ksumTg, attn);
  // final projection -> d_out fp32
  out_gemm<<<dim3(128, 4), blk, 0, stream>>>(attn, WoT, bo, (float*)d_out);
}